// Round 6
// baseline (52.391 us; speedup 1.0000x reference)
//
#include <hip/hip_runtime.h>
#include <math.h>

#define Bb 4
#define Mm 8192
#define Kk 64
#define Cc 32
#define Nn 64
#define Pp 28

#define OFF_PSDF  (Bb*Mm)                          // 32768
#define OFF_INTER (Bb*Mm + Bb*Mm*Kk)               // 2129920
#define OFF_SD    (Bb*Mm + Bb*Mm*Kk + Bb*Mm*Cc)    // 3178496

#define W40    57.707801635558535f      // 40*log2(e)
#define NL2_40 (-0.017328679513998632f) // -ln2/40
#define S75    108.20212806667225f      // 75*log2(e)

typedef float f32x2 __attribute__((ext_vector_type(2)));
typedef float f32x4 __attribute__((ext_vector_type(4)));

struct Rad12 { float v[12]; };

__device__ __forceinline__ float fexp2(float x){ return __builtin_amdgcn_exp2f(x); }
__device__ __forceinline__ float frcp(float x){ return __builtin_amdgcn_rcpf(x); }
__device__ __forceinline__ f32x2 pk_fma(f32x2 a, f32x2 b, f32x2 c){
    f32x2 d; asm("v_pk_fma_f32 %0, %1, %2, %3" : "=v"(d) : "v"(a), "v"(b), "v"(c)); return d;
}

// ---------------- Kernel 0: expand curves + params into workspace ----------
// thread g -> k = g&63 (coalesced), n = (g>>6)&63, b = g>>12
// ws_c  [b][j=n>>1][k][4] = {m2x_e, m2x_o, m2y_e, m2y_o}
// ws_cq [b][j][k][2]      = {csq_e, csq_o}
__global__ __launch_bounds__(256)
void curve_prep(const float* __restrict__ pp, Rad12 rad,
                float* __restrict__ ws_c, float* __restrict__ ws_cq,
                float* __restrict__ params_ws)
{
    const int g = blockIdx.x * 256 + threadIdx.x;   // 16384 threads
    const int k = g & 63;
    const int n = (g >> 6) & 63;
    const int b = g >> 12;

#define PP(p) pp[((b * Pp) + (p)) * Kk + k]

    const int s  = n >> 4;
    const int it = n & 15;
    const float t = (float)it * 0.0625f;            // exact i/16
    const int s1 = (s + 1) & 3;

    float r0 = fabsf(PP(8 + 3 * s + 0));
    float r1 = fabsf(PP(8 + 3 * s + 1));
    float r2 = fabsf(PP(8 + 3 * s + 2));
    float r3 = fabsf(PP(8 + 3 * s1 + 0));
    float w1 = fabsf(PP(20 + 2 * s + 0));
    float w2 = fabsf(PP(20 + 2 * s + 1));

    float a0 = rad.v[3 * s + 0], a1 = rad.v[3 * s + 1];
    float a2 = rad.v[3 * s + 2], a3 = rad.v[3 * s1 + 0];

    float P0x = cosf(a0) * r0, P0y = sinf(a0) * r0;
    float P1x = cosf(a1) * r1, P1y = sinf(a1) * r1;
    float P2x = cosf(a2) * r2, P2y = sinf(a2) * r2;
    float P3x = cosf(a3) * r3, P3y = sinf(a3) * r3;

    float omt = 1.0f - t;
    float b0 = omt * omt * omt;
    float b1 = (3.0f * t) * (omt * omt);
    float b2 = (3.0f * (t * t)) * omt;
    float b3 = t * t * t;
    float bw1 = b1 * w1, bw2 = b2 * w2;
    float den = ((b0 + bw1) + bw2) + b3;
    float nx  = ((b0 * P0x + bw1 * P1x) + bw2 * P2x) + b3 * P3x;
    float ny  = ((b0 * P0y + bw1 * P1y) + bw2 * P2y) + b3 * P3y;

    float cx = nx / den, cy = ny / den;
    const int j = n >> 1, h = n & 1;
    float* base = ws_c + (((b * 32 + j) * 64) + k) * 4;
    base[h]     = -2.0f * cx;
    base[2 + h] = -2.0f * cy;
    ws_cq[(((b * 32 + j) * 64) + k) * 2 + h] = cx * cx + cy * cy;

    if (n < 8) {
        float val;
        if (n < 4) {
            float q0 = PP(0), q1 = PP(1), q2 = PP(2), q3 = PP(3);
            float nrm = sqrtf(q0 * q0 + q1 * q1 + q2 * q2 + q3 * q3);
            val = PP(n) / nrm;
        } else {
            val = PP(n);        // p=4..6 trans, p=7 height
        }
        params_ws[(b * Kk + k) * 8 + n] = val;
    }
#undef PP
}

// ---------------- Kernel 1: per-primitive SDF (phase 1) --------------------
// block = 1024 threads = 16 waves; each wave = 4 points (lane = primitive k).
// LDS: s_c 32 KB curve quads, s_q 16 KB csq pairs  -> 48 KB, 2 blocks/CU.
__global__ __launch_bounds__(1024, 8)
void csg_p1(const float* __restrict__ pts,
            const float* __restrict__ ws_c, const float* __restrict__ ws_cq,
            const float* __restrict__ params_ws,
            float* __restrict__ occ_ws, float* __restrict__ out)
{
    __shared__ __align__(16) float s_c[8192];   // [j][k][4]
    __shared__ __align__(16) float s_q[4096];   // [j][k][2]

    const int tid = threadIdx.x;
    const int bid = blockIdx.x;
    const int b   = bid >> 7;                  // 128 blocks per batch
    const int m0  = (bid & 127) << 6;          // 64 points per block

    {
        const float4* cs = (const float4*)(ws_c + (size_t)b * 8192);
        ((float4*)s_c)[tid]        = cs[tid];
        ((float4*)s_c)[tid + 1024] = cs[tid + 1024];
        ((float4*)s_q)[tid] = ((const float4*)(ws_cq + (size_t)b * 4096))[tid];
    }
    __syncthreads();

    const int wid  = tid >> 6;
    const int lane = tid & 63;
    const int pt0  = b * Mm + m0 + (wid << 2);
    const int k    = lane;

    const float4* prm4 = (const float4*)(params_ws + ((b << 6) + k) * 8);
    float4 q4 = prm4[0];   // qw qx qy qz (normalized)
    float4 t4 = prm4[1];   // tx ty tz height

    const float4* pts4 = (const float4*)(pts + (size_t)pt0 * 3);
    float4 A = pts4[0], Bv = pts4[1], Cv = pts4[2];
    float pxs[4] = {A.x, A.w, Bv.z, Cv.y};
    float pys[4] = {A.y, Bv.x, Bv.w, Cv.z};
    float pzs[4] = {A.z, Bv.y, Cv.x, Cv.w};

    f32x2 plx2[4], ply2[4];
    float plzv[4], psq[4];
    float vx = -q4.y, vy = -q4.z, vz = -q4.w, qw = q4.x;
#pragma unroll
    for (int p = 0; p < 4; ++p) {
        float px = pxs[p] - t4.x, py = pys[p] - t4.y, pz = pzs[p] - t4.z;
        float t1x = 2.0f * (vy * pz - vz * py);
        float t1y = 2.0f * (vz * px - vx * pz);
        float t1z = 2.0f * (vx * py - vy * px);
        float plx = px + qw * t1x + (vy * t1z - vz * t1y);
        float ply = py + qw * t1y + (vz * t1x - vx * t1z);
        plzv[p]   = pz + qw * t1z + (vx * t1y - vy * t1x);
        psq[p]    = plx * plx + ply * ply;
        plx2[p].x = plx; plx2[p].y = plx;
        ply2[p].x = ply; ply2[p].y = ply;
    }

    // best = min_n (csq - 2*dot), psq added at end (bit-identical, strict-<)
    float best[4] = {1e30f, 1e30f, 1e30f, 1e30f};
    float bcsq[4] = {0.0f, 0.0f, 0.0f, 0.0f};
    const f32x4* cdp = ((const f32x4*)s_c) + k;     // stride 64 -> 1KB imm
    const f32x2* cqp = ((const f32x2*)s_q) + k;     // stride 64 -> 512B imm
#pragma unroll
    for (int j = 0; j < 32; ++j) {
        f32x4 cd  = cdp[j * 64];
        f32x2 cq2 = cqp[j * 64];
        f32x2 cx2 = cd.xy, cy2 = cd.zw;
#pragma unroll
        for (int p = 0; p < 4; ++p) {
            f32x2 d = pk_fma(cx2, plx2[p], pk_fma(cy2, ply2[p], cq2));
            if (d.x < best[p]) { best[p] = d.x; bcsq[p] = cq2.x; }
            if (d.y < best[p]) { best[p] = d.y; bcsq[p] = cq2.y; }
        }
    }

#pragma unroll
    for (int p = 0; p < 4; ++p) {
        float d2    = psq[p] + best[p];
        float ud    = sqrtf(fmaxf(d2, 0.0f) + 1e-12f);
        float sgn   = (sqrtf(psq[p]) <= sqrtf(bcsq[p])) ? -1.0f : 1.0f;
        float sdf2d = sgn * ud;
        float dzv   = fabsf(plzv[p]) - t4.w;
        float inner = fminf(fmaxf(sdf2d, dzv), 0.0f);
        float r1m   = fmaxf(sdf2d, 0.0f), r2m = fmaxf(dzv, 0.0f);
        float psdf  = inner + sqrtf(r1m * r1m + r2m * r2m + 1e-12f);
        out[OFF_PSDF + (pt0 + p) * Kk + k] = psdf;
        out[OFF_SD   + (pt0 + p) * Kk + k] = ud;
        occ_ws[(size_t)(pt0 + p) * Kk + k] = frcp(1.0f + fexp2(S75 * psdf));
    }
}

// ---------------- Kernel 2: intersection/union (phase 2) -------------------
// block = 256 threads = 4 waves; each wave = 4 points; lane = (khalf, c).
// LDS: s_iw 16 KB prescaled pairs, s_oq 4 KB occ quads -> 20 KB, 8 blocks/CU.
__global__ __launch_bounds__(256, 8)
void csg_p2(const float* __restrict__ iw_g, const float* __restrict__ uw_g,
            const int* __restrict__ flag, const float* __restrict__ occ_ws,
            float* __restrict__ out)
{
    __shared__ __align__(16) float2 s_iw[2048];   // [k*32+c] = (-40log2e*iw, (iw-1)*40log2e... ) pairs
    __shared__ __align__(16) float4 s_oq[256];    // [pp*32+j] = {oA_p0,oB_p0,oA_p1,oB_p1}

    const int tid = threadIdx.x;
    const int bid = blockIdx.x;
    const int b   = bid >> 9;                  // 512 blocks per batch
    const int m0  = (bid & 511) << 4;          // 16 points per block
    const int pt_base = b * Mm + m0;

    // ---- stage LDS ----
#pragma unroll
    for (int i = 0; i < 8; ++i) {
        int idx = tid + i * 256;
        float w = iw_g[b * 2048 + idx];
        s_iw[idx] = make_float2(w * (-W40), (w - 1.0f) * W40);
    }
    {
        const int pp = tid >> 5, j = tid & 31;
        const float* oA = occ_ws + (size_t)(pt_base + pp * 2) * Kk;
        float4 q;
        q.x = oA[j];       q.y = oA[32 + j];
        q.z = oA[64 + j];  q.w = oA[96 + j];
        s_oq[pp * 32 + j] = q;
    }
    __syncthreads();

    const int wid  = tid >> 6;
    const int lane = tid & 63;
    const int pt0  = pt_base + (wid << 2);
    const int c    = lane & 31;
    const bool hi  = lane >= 32;
    const int kb   = hi ? 32 : 0;

    const float4* oqa = s_oq + (wid << 6);          // pts 0,1 : [j]
    const float4* oqb = oqa + 32;                   // pts 2,3 : [j]
    const float2* iwp = s_iw + (kb << 5) + c;       // [j*32]

    const int training = flag[0];
    float inter[4];
    if (training) {
        float sw[4]  = {0, 0, 0, 0};
        float swp[4] = {0, 0, 0, 0};
#pragma unroll
        for (int j = 0; j < 32; ++j) {
            float4 qa = oqa[j];
            float4 qb = oqb[j];
            float2 wv = iwp[j * 32];
            float os[4];
            os[0] = hi ? qa.y : qa.x;
            os[1] = hi ? qa.w : qa.z;
            os[2] = hi ? qb.y : qb.x;
            os[3] = hi ? qb.w : qb.z;
#pragma unroll
            for (int p = 0; p < 4; ++p) {
                float pre = fmaf(wv.x, os[p], wv.y);   // = -40*log2e * pre_i
                float e   = fexp2(pre);                 // in (0,1]: safe
                sw[p]  += e;
                swp[p]  = fmaf(e, pre, swp[p]);
            }
        }
#pragma unroll
        for (int p = 0; p < 4; ++p) {
            float swt  = sw[p]  + __shfl_xor(sw[p], 32, 64);
            float swpt = swp[p] + __shfl_xor(swp[p], 32, 64);
            inter[p] = swpt * frcp(swt) * NL2_40;
        }
    } else {
        float mx[4] = {-1e30f, -1e30f, -1e30f, -1e30f};
#pragma unroll
        for (int j = 0; j < 32; ++j) {
            float4 qa = oqa[j];
            float4 qb = oqb[j];
            float2 wv = iwp[j * 32];
            float os[4];
            os[0] = hi ? qa.y : qa.x;
            os[1] = hi ? qa.w : qa.z;
            os[2] = hi ? qb.y : qb.x;
            os[3] = hi ? qb.w : qb.z;
#pragma unroll
            for (int p = 0; p < 4; ++p)
                mx[p] = fmaxf(mx[p], fmaf(wv.x, os[p], wv.y));
        }
#pragma unroll
        for (int p = 0; p < 4; ++p) {
            float m2 = fmaxf(mx[p], __shfl_xor(mx[p], 32, 64));
            inter[p] = m2 * NL2_40;                 // min_k pre_i
        }
    }

    if (lane < Cc) {
#pragma unroll
        for (int p = 0; p < 4; ++p)
            out[OFF_INTER + (pt0 + p) * Cc + c] = inter[p];
    }

    // ---- union over c (softmax / max) ----
    float uwv = uw_g[b * Cc + c];
    float resv[4];
    if (training) {
#pragma unroll
        for (int p = 0; p < 4; ++p) {
            float pu  = uwv * inter[p];
            float e   = fexp2(W40 * pu);            // exp(40*pre_u), <= e^40: safe
            float num = e * pu, den = e;
#pragma unroll
            for (int msk = 16; msk >= 1; msk >>= 1) {
                num += __shfl_xor(num, msk, 64);
                den += __shfl_xor(den, msk, 64);
            }
            resv[p] = num * frcp(den);
        }
    } else {
#pragma unroll
        for (int p = 0; p < 4; ++p) {
            float pu = uwv * inter[p];
#pragma unroll
            for (int msk = 16; msk >= 1; msk >>= 1)
                pu = fmaxf(pu, __shfl_xor(pu, msk, 64));
            resv[p] = pu;
        }
    }
    if (lane == 0)
        *(float4*)(out + pt0) = make_float4(resv[0], resv[1], resv[2], resv[3]);
}

// ---------------- host launch ----------------------------------------------
extern "C" void kernel_launch(void* const* d_in, const int* in_sizes, int n_in,
                              void* d_out, int out_size, void* d_ws, size_t ws_size,
                              hipStream_t stream)
{
    const float* pts  = (const float*)d_in[0];
    const float* pp   = (const float*)d_in[1];
    const float* iw   = (const float*)d_in[2];
    const float* uw   = (const float*)d_in[3];
    const int*   flag = (const int*)d_in[4];
    float* out = (float*)d_out;

    float* ws_c   = (float*)d_ws;          // 32768 floats (128 KB)
    float* ws_cq  = ws_c + 32768;          // 16384 floats (64 KB)
    float* params = ws_cq + 16384;         // 2048 floats (8 KB)
    float* occ_ws = params + 2048;         // 2 M floats (8 MB)

    // control radians with host libm (matches CPython math module)
    Rad12 rad;
    const double th = M_PI * 2.0 / 16.0 + atan(tan(2.0 * M_PI / 16.0) / 3.0);
    for (int i = 0; i < 4; ++i) {
        double base = 2.0 * M_PI / 4.0 * (double)i;
        rad.v[3 * i + 0] = (float)base;
        rad.v[3 * i + 1] = (float)(base + th);
        rad.v[3 * i + 2] = (float)(2.0 * M_PI / 4.0 * (double)(i + 1) - th);
    }

    curve_prep<<<64, 256, 0, stream>>>(pp, rad, ws_c, ws_cq, params);
    csg_p1<<<Bb * Mm / 64, 1024, 0, stream>>>(pts, ws_c, ws_cq, params,
                                              occ_ws, out);
    csg_p2<<<Bb * Mm / 16, 256, 0, stream>>>(iw, uw, flag, occ_ws, out);
}

// Round 7
// 42.524 us; speedup vs baseline: 1.2320x; 1.2320x over previous
//
#include <hip/hip_runtime.h>
#include <math.h>

#define Bb 4
#define Mm 8192
#define Kk 64
#define Cc 32
#define Pp 28

#define OFF_PSDF  (Bb*Mm)                          // 32768
#define OFF_INTER (Bb*Mm + Bb*Mm*Kk)               // 2129920
#define OFF_SD    (Bb*Mm + Bb*Mm*Kk + Bb*Mm*Cc)    // 3178496

#define W40    57.707801635558535f      // 40*log2(e)
#define NL2_40 (-0.017328679513998632f) // -ln2/40
#define S75    108.20212806667225f      // 75*log2(e)
#define EPS_OCC 1e-6f

struct Rad12 { float v[12]; };

__device__ __forceinline__ float fexp2(float x){ return __builtin_amdgcn_exp2f(x); }
__device__ __forceinline__ float frcp(float x){ return __builtin_amdgcn_rcpf(x); }

// ---------------- Kernel 0: expand curves + params + (k,c) sums ------------
// thread g -> k = g&63 (coalesced), n = (g>>6)&63, b = g>>12
// ws_c  [b][j=n>>1][k][4] = {m2x_e, m2x_o, m2y_e, m2y_o}
// ws_cq [b][j][k][2]      = {csq_e, csq_o}
__global__ __launch_bounds__(256)
void curve_prep(const float* __restrict__ pp, const float* __restrict__ iw_g,
                Rad12 rad,
                float* __restrict__ ws_c, float* __restrict__ ws_cq,
                float* __restrict__ params_ws, float2* __restrict__ st_ws)
{
    const int g = blockIdx.x * 256 + threadIdx.x;   // 16384 threads
    const int k = g & 63;
    const int n = (g >> 6) & 63;
    const int b = g >> 12;

#define PP(p) pp[((b * Pp) + (p)) * Kk + k]

    const int s  = n >> 4;
    const int it = n & 15;
    const float t = (float)it * 0.0625f;            // exact i/16
    const int s1 = (s + 1) & 3;

    float r0 = fabsf(PP(8 + 3 * s + 0));
    float r1 = fabsf(PP(8 + 3 * s + 1));
    float r2 = fabsf(PP(8 + 3 * s + 2));
    float r3 = fabsf(PP(8 + 3 * s1 + 0));
    float w1 = fabsf(PP(20 + 2 * s + 0));
    float w2 = fabsf(PP(20 + 2 * s + 1));

    float a0 = rad.v[3 * s + 0], a1 = rad.v[3 * s + 1];
    float a2 = rad.v[3 * s + 2], a3 = rad.v[3 * s1 + 0];

    float P0x = cosf(a0) * r0, P0y = sinf(a0) * r0;
    float P1x = cosf(a1) * r1, P1y = sinf(a1) * r1;
    float P2x = cosf(a2) * r2, P2y = sinf(a2) * r2;
    float P3x = cosf(a3) * r3, P3y = sinf(a3) * r3;

    float omt = 1.0f - t;
    float b0 = omt * omt * omt;
    float b1 = (3.0f * t) * (omt * omt);
    float b2 = (3.0f * (t * t)) * omt;
    float b3 = t * t * t;
    float bw1 = b1 * w1, bw2 = b2 * w2;
    float den = ((b0 + bw1) + bw2) + b3;
    float nx  = ((b0 * P0x + bw1 * P1x) + bw2 * P2x) + b3 * P3x;
    float ny  = ((b0 * P0y + bw1 * P1y) + bw2 * P2y) + b3 * P3y;

    float cx = nx / den, cy = ny / den;
    const int j = n >> 1, h = n & 1;
    float* base = ws_c + (((b * 32 + j) * 64) + k) * 4;
    base[h]     = -2.0f * cx;
    base[2 + h] = -2.0f * cy;
    ws_cq[(((b * 32 + j) * 64) + k) * 2 + h] = cx * cx + cy * cy;

    if (n < 8) {
        float val;
        if (n < 4) {
            float q0 = PP(0), q1 = PP(1), q2 = PP(2), q3 = PP(3);
            float nrm = sqrtf(q0 * q0 + q1 * q1 + q2 * q2 + q3 * q3);
            val = PP(n) / nrm;
        } else {
            val = PP(n);        // p=4..6 trans, p=7 height
        }
        params_ws[(b * Kk + k) * 8 + n] = val;
    }
#undef PP

    // fold-in: per-(b,c) saturated-occ softmin sums S0,T0
    if (blockIdx.x == 0 && threadIdx.x < 128) {
        const int tb = threadIdx.x >> 5, tc = threadIdx.x & 31;
        float S = 0.0f, T = 0.0f;
        for (int kk = 0; kk < 64; ++kk) {
            float w   = iw_g[tb * 2048 + kk * 32 + tc];
            float b40 = (w - 1.0f) * W40;
            float e   = fexp2(b40);
            S += e;
            T  = fmaf(e, b40, T);
        }
        st_ws[threadIdx.x] = make_float2(S, T);
    }
}

// ---------------- Kernel 1: fused main ------------------------------------
// block = 512 threads = 8 waves; each wave = 8 points (ph1 lane = primitive k).
// LDS pool (floats, 49408 B total):
//   ph1: [0,8192) curve quads [j][k][4] ; [8192,12288) csq [j][k][2]
//   ph2 (after barrier, aliased): [0,4096) occ [k][pt] XOR-swizzled;
//        [4096,8192) wv float2[k*32+c]; [8192,12288) E0 float2[k*32+c];
//        [12288,12352) S0T0 float2[c]
__global__ __launch_bounds__(512, 6)
void csg_main(const float* __restrict__ pts, const float* __restrict__ iw_g,
              const float* __restrict__ uw_g, const int* __restrict__ flag,
              const float* __restrict__ ws_c, const float* __restrict__ ws_cq,
              const float* __restrict__ params_ws, const float2* __restrict__ st_ws,
              float* __restrict__ out)
{
    __shared__ __align__(16) float s_pool[12352];

    const int tid = threadIdx.x;
    const int bid = blockIdx.x;
    const int b   = bid >> 7;                  // 128 blocks per batch
    const int m0  = (bid & 127) << 6;          // 64 points per block

    // ---- stage ph1 LDS ----
    {
        const float4* cs = (const float4*)(ws_c + (size_t)b * 8192);
        float4* cd = (float4*)s_pool;
#pragma unroll
        for (int i = 0; i < 4; ++i) cd[tid + i * 512] = cs[tid + i * 512];
        const float4* qs = (const float4*)(ws_cq + (size_t)b * 4096);
        float4* qd = (float4*)&s_pool[8192];
#pragma unroll
        for (int i = 0; i < 2; ++i) qd[tid + i * 512] = qs[tid + i * 512];
    }
    __syncthreads();

    const int wid  = tid >> 6;
    const int lane = tid & 63;
    const int k    = lane;
    const int pt0  = b * Mm + m0 + (wid << 3);   // 8 pts per wave

    const float4* prm4 = (const float4*)(params_ws + ((b << 6) + k) * 8);
    float4 q4 = prm4[0];   // qw qx qy qz (normalized)
    float4 t4 = prm4[1];   // tx ty tz height

    // 8 points = 24 floats = 6 float4 (same addr all lanes -> scalar loads)
    float fl[24];
    {
        const float4* p4 = (const float4*)(pts + (size_t)pt0 * 3);
#pragma unroll
        for (int i = 0; i < 6; ++i) {
            float4 v = p4[i];
            fl[i * 4 + 0] = v.x; fl[i * 4 + 1] = v.y;
            fl[i * 4 + 2] = v.z; fl[i * 4 + 3] = v.w;
        }
    }

    float plx[8], ply[8], plzv[8], psq[8];
    {
        float vx = -q4.y, vy = -q4.z, vz = -q4.w, qw = q4.x;
#pragma unroll
        for (int p = 0; p < 8; ++p) {
            float px = fl[3 * p + 0] - t4.x;
            float py = fl[3 * p + 1] - t4.y;
            float pz = fl[3 * p + 2] - t4.z;
            float t1x = 2.0f * (vy * pz - vz * py);
            float t1y = 2.0f * (vz * px - vx * pz);
            float t1z = 2.0f * (vx * py - vy * px);
            plx[p]  = px + qw * t1x + (vy * t1z - vz * t1y);
            ply[p]  = py + qw * t1y + (vz * t1x - vx * t1z);
            plzv[p] = pz + qw * t1z + (vx * t1y - vy * t1x);
            psq[p]  = plx[p] * plx[p] + ply[p] * ply[p];
        }
    }

    // best = min_n (csq - 2*dot); psq added at end (bit-identical, strict-<)
    float best[8], bcsq[8];
#pragma unroll
    for (int p = 0; p < 8; ++p) { best[p] = 1e30f; bcsq[p] = 0.0f; }
    {
        const float4* cdp = (const float4*)&s_pool[k * 4];          // j*1024B
        const float2* cqp = (const float2*)&s_pool[8192 + k * 2];   // j*512B
#pragma unroll 8
        for (int j = 0; j < 32; ++j) {
            float4 cd  = cdp[j * 64];
            float2 cq2 = cqp[j * 64];
#pragma unroll
            for (int p = 0; p < 8; ++p) {
                float da = fmaf(cd.x, plx[p], fmaf(cd.z, ply[p], cq2.x));
                if (da < best[p]) { best[p] = da; bcsq[p] = cq2.x; }
                float db = fmaf(cd.y, plx[p], fmaf(cd.w, ply[p], cq2.y));
                if (db < best[p]) { best[p] = db; bcsq[p] = cq2.y; }
            }
        }
    }

    float occ[8];
    unsigned long long mask[8];
#pragma unroll
    for (int p = 0; p < 8; ++p) {
        float d2    = psq[p] + best[p];
        float ud    = sqrtf(fmaxf(d2, 0.0f) + 1e-12f);
        float sgn   = (sqrtf(psq[p]) <= sqrtf(bcsq[p])) ? -1.0f : 1.0f;
        float sdf2d = sgn * ud;
        float dzv   = fabsf(plzv[p]) - t4.w;
        float inner = fminf(fmaxf(sdf2d, dzv), 0.0f);
        float r1m   = fmaxf(sdf2d, 0.0f), r2m = fmaxf(dzv, 0.0f);
        float psdf  = inner + sqrtf(r1m * r1m + r2m * r2m + 1e-12f);
        out[OFF_PSDF + (pt0 + p) * Kk + k] = psdf;
        out[OFF_SD   + (pt0 + p) * Kk + k] = ud;
        occ[p]  = frcp(1.0f + fexp2(S75 * psdf));   // sigmoid(-75*psdf)
        mask[p] = __ballot(occ[p] > EPS_OCC);
    }

    // ---- barrier: curve LDS dead; build ph2 tables ----
    __syncthreads();
    {
        // occ[k][pt] with XOR swizzle (byte col ^ (k&15)<<4) — conflict-light
        const int key  = (k & 15) << 4;
        const int colb = wid << 5;                 // 8 pts * 4B
        char* basep = (char*)s_pool + k * 256;
        *(float4*)(basep + ((colb)      ^ key)) = make_float4(occ[0], occ[1], occ[2], occ[3]);
        *(float4*)(basep + ((colb + 16) ^ key)) = make_float4(occ[4], occ[5], occ[6], occ[7]);
    }
#pragma unroll
    for (int i = 0; i < 4; ++i) {
        int idx = tid + i * 512;                   // (k,c) = idx>>5, idx&31
        float w  = iw_g[b * 2048 + idx];
        float a  = w * (-W40);
        float bb = (w - 1.0f) * W40;
        float e0 = fexp2(bb);
        ((float2*)&s_pool[4096])[idx] = make_float2(a, bb);
        ((float2*)&s_pool[8192])[idx] = make_float2(e0, e0 * bb);
    }
    if (tid < 32) ((float2*)&s_pool[12288])[tid] = st_ws[b * 32 + tid];
    __syncthreads();

    // ================= Phase 2: lane = c (duplicated across halves) ========
    const int training = flag[0];
    const int c = lane & 31;
    const float2* wvt = (const float2*)&s_pool[4096];
    const float2* e0t = (const float2*)&s_pool[8192];

    float inter[8];
    if (training) {
        float2 s0t0 = ((const float2*)&s_pool[12288])[c];
#pragma unroll
        for (int p = 0; p < 8; ++p) {
            unsigned long long m = mask[p];
            const int pt4 = ((wid << 3) + p) << 2;   // pt_local * 4 bytes
            float sw = s0t0.x, swp = s0t0.y;
            while (m) {
                int kk = __builtin_ctzll(m); m &= m - 1;
                float osv = *(const float*)((const char*)s_pool +
                              kk * 256 + (pt4 ^ ((kk & 15) << 4)));
                float2 wv = wvt[kk * 32 + c];
                float2 e0 = e0t[kk * 32 + c];
                float pre = fmaf(wv.x, osv, wv.y);   // = -40*log2e * pre_i
                float e   = fexp2(pre);               // in (0,1]: safe
                sw  += (e - e0.x);
                swp += fmaf(e, pre, -e0.y);
            }
            inter[p] = swp * frcp(sw) * NL2_40;
        }
    } else {
        const int kb = lane & 32;
#pragma unroll
        for (int p = 0; p < 8; ++p) {
            const int pt4 = ((wid << 3) + p) << 2;
            float mx = -1e30f;
            for (int j = 0; j < 32; ++j) {
                int row = kb + j;
                float osv = *(const float*)((const char*)s_pool +
                              row * 256 + (pt4 ^ ((row & 15) << 4)));
                float2 wv = wvt[row * 32 + c];
                mx = fmaxf(mx, fmaf(wv.x, osv, wv.y));
            }
            mx = fmaxf(mx, __shfl_xor(mx, 32, 64));
            inter[p] = mx * NL2_40;                  // min_k pre_i
        }
    }

    if (lane < Cc) {
#pragma unroll
        for (int p = 0; p < 8; ++p)
            out[OFF_INTER + (pt0 + p) * Cc + c] = inter[p];
    }

    // ---- union over c (softmax / max), tree within each 32-half ----
    float uwv = uw_g[b * Cc + c];
    float resv[8];
    if (training) {
#pragma unroll
        for (int p = 0; p < 8; ++p) {
            float pu  = uwv * inter[p];
            float e   = fexp2(W40 * pu);             // exp(40*pre_u) <= e^40
            float num = e * pu, den = e;
#pragma unroll
            for (int msk = 16; msk >= 1; msk >>= 1) {
                num += __shfl_xor(num, msk, 64);
                den += __shfl_xor(den, msk, 64);
            }
            resv[p] = num * frcp(den);
        }
    } else {
#pragma unroll
        for (int p = 0; p < 8; ++p) {
            float pu = uwv * inter[p];
#pragma unroll
            for (int msk = 16; msk >= 1; msk >>= 1)
                pu = fmaxf(pu, __shfl_xor(pu, msk, 64));
            resv[p] = pu;
        }
    }
    if (lane == 0) {
        *(float4*)(out + pt0)     = make_float4(resv[0], resv[1], resv[2], resv[3]);
        *(float4*)(out + pt0 + 4) = make_float4(resv[4], resv[5], resv[6], resv[7]);
    }
}

// ---------------- host launch ----------------------------------------------
extern "C" void kernel_launch(void* const* d_in, const int* in_sizes, int n_in,
                              void* d_out, int out_size, void* d_ws, size_t ws_size,
                              hipStream_t stream)
{
    const float* pts  = (const float*)d_in[0];
    const float* pp   = (const float*)d_in[1];
    const float* iw   = (const float*)d_in[2];
    const float* uw   = (const float*)d_in[3];
    const int*   flag = (const int*)d_in[4];
    float* out = (float*)d_out;

    float*  ws_c   = (float*)d_ws;          // 32768 floats (128 KB)
    float*  ws_cq  = ws_c + 32768;          // 16384 floats (64 KB)
    float*  params = ws_cq + 16384;         // 2048 floats (8 KB)
    float2* st_ws  = (float2*)(params + 2048); // 128 float2 (1 KB)

    // control radians with host libm (matches CPython math module)
    Rad12 rad;
    const double th = M_PI * 2.0 / 16.0 + atan(tan(2.0 * M_PI / 16.0) / 3.0);
    for (int i = 0; i < 4; ++i) {
        double base = 2.0 * M_PI / 4.0 * (double)i;
        rad.v[3 * i + 0] = (float)base;
        rad.v[3 * i + 1] = (float)(base + th);
        rad.v[3 * i + 2] = (float)(2.0 * M_PI / 4.0 * (double)(i + 1) - th);
    }

    curve_prep<<<64, 256, 0, stream>>>(pp, iw, rad, ws_c, ws_cq, params, st_ws);
    csg_main<<<Bb * Mm / 64, 512, 0, stream>>>(pts, iw, uw, flag,
                                               ws_c, ws_cq, params, st_ws, out);
}